// Round 7
// baseline (235.237 us; speedup 1.0000x reference)
//
#include <hip/hip_runtime.h>
#include <math.h>

#define NUMPIX 256
#define NUMBIN 367
#define NUMTHETA 360
#define NS 4
#define NT 367
#define NPIX2 (NUMPIX * NUMPIX)          // 65536
#define NANG_SUB (NUMTHETA / NS)         // 90
#define NRAYS_SUB (NANG_SUB * NUMBIN)    // 33030

// 180-degree mirror symmetry: FP[a+180][b] == FP[a][366-b] exactly (same
// bilinear sample points, reversed t order; t-grid is symmetric). All ray
// marches compute only angles [0,180) and emit both the ray and its mirror.
#define NANG_HALF 180
#define NANG_SUBH (NANG_SUB / 2)             // 45

// angle-major ray units: 23 units/angle x 16 rays/unit (bin 367 padded+masked)
#define UPA 23
#define HALF_UNITS (NANG_HALF * UPA)         // 4140 (residual + minv)
#define SUB_UNITS  (NANG_SUBH * UPA)         // 1035 (subset FP)

#define CDET 183.0f
#define CPIX 127.5f
#define TOFF 183.0f                      // (NT-1)/2
#define DEN_EPS 1e-6f
#define EPS_F 2.2204460492503131e-16f    // float64 eps
#define RES2_THRESH 1e-4f                // (0.01)^2
#define INV_DINV (1.0f / 90.0f)          // backproject(ones) == 90 exactly

// quad-interleaved image: element (r,c) = float2(img[r][c], img[r+1][c])
// rows r in [-1,256] stored at +1 (258 rows), cols c in [-1,258] at +1.
// Pixel (py,px) lives at Qf[(py+1)*QW+px+1].x — canonical fk storage.
// NOTE: march clamps coords to [-1,256]; the clamp is the TAIL MASK for
// overshoot lanes of the rounded-up chunk loop. Do NOT remove it.
// Grid-wide-sync fusion abandoned (r10/r11: co-residency not reliable).
// ROUND-2/3 LESSON: no same-LINE contended device atomics where the issuer
// waits on completion — 4129 RMWs to one line ~160 us (r2/r3).
// ROUND-5 LESSON: even a PADDED 64-slot fan-in + last-block select regressed
// (+22 us: contended completion-waits + a single CU writing the output while
// 255 idle). The r1/r4-proven pattern stands: distinct-slot plain stores +
// consumer-side redundant reduce across a dispatch boundary. ZERO atomics.
// ROUND-4/6 LESSON: ~7-9 us per dispatch boundary dominates (~150 us of 222
// at 19 dispatches) — boundary cuts are the lever, but only fusions with NO
// new intra-dispatch synchronization (r5). r7: init++fp_sub(j0) fold (both
// read only f0/sino; zero cross-block deps) — the one remaining safe cut.
#define QW 260                           // float2 stride
#define QROWS 258
#define QN2 (QW * QROWS)                 // 67080 float2
#define QNF (QN2 * 2)                    // 134160 floats

typedef float f4q __attribute__((ext_vector_type(4), aligned(8)));
typedef float f2u __attribute__((ext_vector_type(2), aligned(4)));

// ---- workspace layout (in floats) ----
#define OFF_COS    0
#define OFF_SIN    (OFF_COS + NUMTHETA)            // 360
#define OFF_MINV   (OFF_SIN + NUMTHETA)            // 720
#define OFF_RESP1  (OFF_MINV + NUMTHETA * NUMBIN)  // 4140 block partials
#define OFF_RESP2  (OFF_RESP1 + HALF_UNITS + 4)    // 4140 block partials
#define OFF_Q      (OFF_RESP2 + HALF_UNITS + 4)
#define OFF_QT     (OFF_Q + QNF)
#define OFF_DIFF   (OFF_QT + QNF)                  // working diffs [90,367]
#define OFF_DIFF0  (OFF_DIFF + NRAYS_SUB + 2)      // iter1-j0 diffs (cold path)

// generic t-interval clip: keep c0 + rate*tt within (bLo, bHi)
__device__ __forceinline__ void clip_axis2(float c0, float rate,
                                           float bLo, float bHi,
                                           float& lo, float& hi) {
    if (fabsf(rate) > 1e-6f) {
        float inv = 1.0f / rate;
        float a = (bLo - c0) * inv;
        float b = (bHi - c0) * inv;
        lo = fmaxf(lo, fminf(a, b));
        hi = fminf(hi, fmaxf(a, b));
    } else if (c0 <= bLo || c0 >= bHi) {
        lo = 1e9f; hi = -1e9f;
    }
}

// sampled t-range in 16-sample chunks; coords stay within clamp range
__device__ __forceinline__ int ray_chunks16(float x0, float y0, float ca, float sa,
                                            int& itlo) {
    float lo = -1e9f, hi = 1e9f;
    clip_axis2(x0, -sa, -2.0f, 257.0f, lo, hi);
    clip_axis2(y0,  ca, -2.0f, 257.0f, lo, hi);
    if (hi < lo) { itlo = 0; return 0; }
    int a = (int)floorf(lo + TOFF) - 1; if (a < 0) a = 0;
    int b = (int)ceilf(hi + TOFF) + 1;  if (b > NT - 1) b = NT - 1;
    itlo = a;
    if (b < a) return 0;
    return (b - a + 16) >> 4;
}

struct RaySetup {
    int nc;
    float u, v, du, dv;
    bool useT;
};

__device__ __forceinline__ RaySetup ray_setup_ab(int angle, int bin,
                                                 const float* __restrict__ cosA,
                                                 const float* __restrict__ sinA,
                                                 int slane) {
    RaySetup R;
    float ca = cosA[angle], sa = sinA[angle];
    float s = (float)bin - CDET;
    float x0 = fmaf(s, ca, CPIX);             // x(tt) = x0 - tt*sa
    float y0 = fmaf(s, sa, CPIX);             // y(tt) = y0 + tt*ca
    int itlo;
    R.nc = ray_chunks16(x0, y0, ca, sa, itlo);
    R.useT = fabsf(ca) > fabsf(sa);           // uniform per sub-group
    float u0 = R.useT ? y0 : x0, du = R.useT ? ca : -sa;   // fast (contiguous)
    float v0 = R.useT ? x0 : y0, dv = R.useT ? -sa : ca;   // slow (strided)
    float tt0 = (float)(itlo + slane) - TOFF;
    R.u = fmaf(tt0, du, u0);
    R.v = fmaf(tt0, dv, v0);
    R.du = du; R.dv = dv;
    return R;
}

// one clamped bilinear sample from a quad image
__device__ __forceinline__ float bilin(const float* __restrict__ img,
                                       float u, float v) {
    float uc = fminf(fmaxf(u, -1.0f), 256.0f);
    float vc = fminf(fmaxf(v, -1.0f), 256.0f);
    float fu = floorf(uc), fv = floorf(vc);
    float wu = uc - fu, wv = vc - fv;
    int idx = (int)fmaf(fv, (float)QW, fu);
    f4q q = *(const f4q*)(img + idx * 2);
    float t = fmaf(wu, q.z - q.x, q.x);
    float b = fmaf(wu, q.w - q.y, q.y);
    return fmaf(wv, b - t, t);
}

// chunk loop unrolled x4 with 4 independent accumulators (r6: latency-bound
// marches want 4 gathers in flight). Sum-order delta ~1e-7 rel.
__device__ __forceinline__ float march(const float* __restrict__ img,
                                       float u, float v, float du, float dv,
                                       int nc) {
    const float du16 = du * 16.0f, dv16 = dv * 16.0f;
    float a0 = 0.0f, a1 = 0.0f, a2 = 0.0f, a3 = 0.0f;
    int ic = 0;
    for (; ic + 3 < nc; ic += 4) {
        a0 += bilin(img, u, v);
        a1 += bilin(img, u + du16, v + dv16);
        a2 += bilin(img, u + du16 * 2.0f, v + dv16 * 2.0f);
        a3 += bilin(img, u + du16 * 3.0f, v + dv16 * 3.0f);
        u += du16 * 4.0f; v += dv16 * 4.0f;
    }
    for (; ic < nc; ++ic) {
        a0 += bilin(img, u, v);
        u += du16; v += dv16;
    }
    return (a0 + a1) + (a2 + a3);
}

// residual block-unit (angle-major): marches 16 rays of fk, returns block
// total of (base + mirror) squared diffs to ALL threads. If gA != nullptr
// and this block's angle is subset-0 (angle%4==0), also emits the iter2-j0
// diffs from the SAME march (dedupe: those rays coincide with residual rays).
__device__ __forceinline__ float res_block_total(
        int unit, const float* __restrict__ Qn, const float* __restrict__ Qt,
        const float* __restrict__ sino,
        const float* __restrict__ cosA, const float* __restrict__ sinA,
        float* partLds, const float* __restrict__ minv, float* __restrict__ gA) {
    const int wid = threadIdx.x >> 6, lane = threadIdx.x & 63;
    const int sub = lane >> 4, slane = lane & 15;
    int angle = unit / UPA;
    int bin = (unit - angle * UPA) * 16 + wid * 4 + sub;
    bool valid = bin < NUMBIN;
    RaySetup R = ray_setup_ab(angle, valid ? bin : 0, cosA, sinA, slane);
    const float* img = (R.useT ? Qt : Qn) + (QW + 1) * 2;
    float acc = march(img, R.u, R.v, R.du, R.dv, valid ? R.nc : 0);
    acc += __shfl_down(acc, 8, 16);
    acc += __shfl_down(acc, 4, 16);
    acc += __shfl_down(acc, 2, 16);
    acc += __shfl_down(acc, 1, 16);
    float d2 = 0.0f;
    if (slane == 0 && valid) {
        int b2 = NUMBIN - 1 - bin;
        float s1 = sino[angle * NUMBIN + bin];
        float s2 = sino[(angle + NANG_HALF) * NUMBIN + b2];
        float d = acc - s1, dm = acc - s2;
        d2 = d * d + dm * dm;
        if (gA != nullptr && (angle & 3) == 0) {
            int ai = angle >> 2;
            gA[ai * NUMBIN + bin] = (s1 - acc) / minv[angle * NUMBIN + bin];
            gA[(ai + NANG_SUBH) * NUMBIN + b2] =
                (s2 - acc) / minv[(angle + NANG_HALF) * NUMBIN + b2];
        }
    }
    d2 += __shfl_down(d2, 16);
    d2 += __shfl_down(d2, 32);
    if (lane == 0) partLds[wid] = d2;
    __syncthreads();
    return partLds[0] + partLds[1] + partLds[2] + partLds[3];
}

// ---------------- init + Minv + iter1-subset-0 FP in one dispatch ----------
// idx-gated portion: trig tables + quad images. unit portion:
//   angle%4 != 0 -> edge-shortcut Minv (own __sincosf; normalizer only).
//   angle%4 == 0 -> FULL mask-march of RAW f0 (clamped scalar gathers, masked
//     weights), producing FP(f0) AND the weight-sum (= this ray's Minv) in
//     one pass -> writes minv + dfA + df0 (pristine cold-branch snapshot).
//     Value-path trig is exact double cos/sin (bit-matches the table), so
//     hot-path numerics are unchanged. Zero cross-block dependencies — the
//     fold only removes a dispatch boundary (r7; r5-proven piece re-applied
//     standalone after the r5 bundle's other two bets were reverted).
__global__ __launch_bounds__(256)
void init_minv_kernel(float* __restrict__ cosA, float* __restrict__ sinA,
                      float* __restrict__ Qf, float* __restrict__ QTf,
                      float* __restrict__ minv,
                      float* __restrict__ dfA, float* __restrict__ df0,
                      const float* __restrict__ f0,
                      const float* __restrict__ sino) {
    int idx = blockIdx.x * blockDim.x + threadIdx.x;
    if (idx < NUMTHETA) {
        float th = (float)((double)idx * 0.017453292519943295);
        cosA[idx] = (float)cos((double)th);
        sinA[idx] = (float)sin((double)th);
    }
    if (idx < QN2) {
        int qr = idx / QW, qc = idx - qr * QW;
        int r = qr - 1, c = qc - 1;                 // r in [-1,256], c in [-1,258]
        bool cv = ((unsigned)c < 256u);
        bool rv0 = ((unsigned)r < 256u), rv1 = ((unsigned)(r + 1) < 256u);
        float a = (cv && rv0) ? f0[r * NUMPIX + c] : 0.0f;
        float b = (cv && rv1) ? f0[(r + 1) * NUMPIX + c] : 0.0f;
        Qf[idx * 2] = a;  Qf[idx * 2 + 1] = b;
        float ta = (cv && rv0) ? f0[c * NUMPIX + r] : 0.0f;
        float tb = (cv && rv1) ? f0[c * NUMPIX + (r + 1)] : 0.0f;
        QTf[idx * 2] = ta;  QTf[idx * 2 + 1] = tb;
    }

    const int lane = threadIdx.x & 63;
    const int wid = threadIdx.x >> 6;
    const int sub = lane >> 4, slane = lane & 15;
    int unit = blockIdx.x;
    int angle = unit / UPA;                  // [0,180), uniform per block
    int bin = (unit - angle * UPA) * 16 + wid * 4 + sub;
    bool valid = bin < NUMBIN;

    if ((angle & 3) == 0) {
        // subset-0: full mask-march of raw f0 (value + weight-sum together)
        double thd = (double)angle * 0.017453292519943295;
        float ca = (float)cos(thd);          // bit-matches cosA table
        float sa = (float)sin(thd);
        float s = (float)(valid ? bin : 0) - CDET;
        float x0 = fmaf(s, ca, CPIX);
        float y0 = fmaf(s, sa, CPIX);
        float lo = -1e9f, hi = 1e9f;
        clip_axis2(x0, -sa, -2.0f, 257.0f, lo, hi);
        clip_axis2(y0,  ca, -2.0f, 257.0f, lo, hi);
        float val = 0.0f, wsum = 0.0f;
        if (hi >= lo) {
            int itA = (int)floorf(lo + TOFF) - 1; if (itA < 0) itA = 0;
            int itB = (int)ceilf(hi + TOFF) + 1;  if (itB > NT - 1) itB = NT - 1;
            #pragma unroll 1
            for (int base = itA; base <= itB; base += 16) {
                int t = base + slane;
                float tt = (float)t - TOFF;
                float x = fmaf(-tt, sa, x0);
                float y = fmaf(tt, ca, y0);
                float fx = floorf(x), fy = floorf(y);
                float wx = x - fx, wy = y - fy;
                int c0 = (int)fx, r0 = (int)fy;
                float ux0 = ((unsigned)c0 < 256u) ? (1.0f - wx) : 0.0f;
                float ux1 = ((unsigned)(c0 + 1) < 256u) ? wx : 0.0f;
                float uy0 = ((unsigned)r0 < 256u) ? (1.0f - wy) : 0.0f;
                float uy1 = ((unsigned)(r0 + 1) < 256u) ? wy : 0.0f;
                int c0c = c0 < 0 ? 0 : (c0 > 255 ? 255 : c0);
                int c1c = c0 + 1 < 0 ? 0 : (c0 + 1 > 255 ? 255 : c0 + 1);
                int r0c = r0 < 0 ? 0 : (r0 > 255 ? 255 : r0);
                int r1c = r0 + 1 < 0 ? 0 : (r0 + 1 > 255 ? 255 : r0 + 1);
                float F00 = f0[r0c * NUMPIX + c0c];
                float F01 = f0[r0c * NUMPIX + c1c];
                float F10 = f0[r1c * NUMPIX + c0c];
                float F11 = f0[r1c * NUMPIX + c1c];
                if (t <= itB) {
                    val += uy0 * fmaf(ux0, F00, ux1 * F01)
                         + uy1 * fmaf(ux0, F10, ux1 * F11);
                    wsum += (ux0 + ux1) * (uy0 + uy1);
                }
            }
        }
        #pragma unroll
        for (int off = 8; off; off >>= 1) {
            val  += __shfl_down(val, off, 16);
            wsum += __shfl_down(wsum, off, 16);
        }
        if (slane == 0 && valid) {
            float m = fmaxf(wsum, DEN_EPS);
            int b2 = NUMBIN - 1 - bin;
            minv[angle * NUMBIN + bin] = m;
            minv[(angle + NANG_HALF) * NUMBIN + b2] = m;    // mirror identical
            int ai = angle >> 2;
            float g1 = (sino[angle * NUMBIN + bin] - val) / m;
            float g2 = (sino[(angle + NANG_HALF) * NUMBIN + b2] - val) / m;
            dfA[ai * NUMBIN + bin] = g1;
            df0[ai * NUMBIN + bin] = g1;
            dfA[(ai + NANG_SUBH) * NUMBIN + b2] = g2;
            df0[(ai + NANG_SUBH) * NUMBIN + b2] = g2;
        }
        return;
    }

    // other angles: edge-shortcut Minv (interior samples counted exactly)
    float th = (float)((double)angle * 0.017453292519943295);
    float ca, sa;
    __sincosf(th, &sa, &ca);
    float s = (float)(valid ? bin : 0) - CDET;
    float x0 = fmaf(s, ca, CPIX);
    float y0 = fmaf(s, sa, CPIX);
    float acc = 0.0f;
    int count = 0;
    float lo = -1e9f, hi = 1e9f;
    clip_axis2(x0, -sa, -2.0f, 257.0f, lo, hi);
    clip_axis2(y0,  ca, -2.0f, 257.0f, lo, hi);
    int e1a = 0, e1b = -1, e2a = 0, e2b = -1;
    if (hi >= lo) {
        int itA = (int)floorf(lo + TOFF) - 1; if (itA < 0) itA = 0;
        int itB = (int)ceilf(hi + TOFF) + 1;  if (itB > NT - 1) itB = NT - 1;
        if (itB >= itA) {
            // strict interior: both coords in (0.05, 254.95) -> weight exactly 1
            float ilo = -1e9f, ihi = 1e9f;
            clip_axis2(x0, -sa, 0.05f, 254.95f, ilo, ihi);
            clip_axis2(y0,  ca, 0.05f, 254.95f, ilo, ihi);
            int jA = 1, jB = 0;
            if (ihi >= ilo) {
                jA = (int)ceilf(ilo + TOFF) + 1;
                jB = (int)floorf(ihi + TOFF) - 1;
                if (jA < itA) jA = itA;
                if (jB > itB) jB = itB;
            }
            if (jB >= jA) {
                count = jB - jA + 1;
                e1a = itA; e1b = jA - 1;
                e2a = jB + 1; e2b = itB;
            } else {
                e1a = itA; e1b = itB;       // no interior: one full edge loop
            }
        }
    }
    #pragma unroll 1
    for (int base = e1a; base <= e1b; base += 16) {
        int t = base + slane;
        float tt = (float)t - TOFF;
        float x = fmaf(-tt, sa, x0);
        float y = fmaf(tt, ca, y0);
        float fx = floorf(x), fy = floorf(y);
        float wx = x - fx, wy = y - fy;
        int c0 = (int)fx, r0 = (int)fy;
        float ux = (((unsigned)c0 < 256u) ? (1.0f - wx) : 0.0f) +
                   (((unsigned)(c0 + 1) < 256u) ? wx : 0.0f);
        float uy = (((unsigned)r0 < 256u) ? (1.0f - wy) : 0.0f) +
                   (((unsigned)(r0 + 1) < 256u) ? wy : 0.0f);
        if (t <= e1b) acc += ux * uy;
    }
    #pragma unroll 1
    for (int base = e2a; base <= e2b; base += 16) {
        int t = base + slane;
        float tt = (float)t - TOFF;
        float x = fmaf(-tt, sa, x0);
        float y = fmaf(tt, ca, y0);
        float fx = floorf(x), fy = floorf(y);
        float wx = x - fx, wy = y - fy;
        int c0 = (int)fx, r0 = (int)fy;
        float ux = (((unsigned)c0 < 256u) ? (1.0f - wx) : 0.0f) +
                   (((unsigned)(c0 + 1) < 256u) ? wx : 0.0f);
        float uy = (((unsigned)r0 < 256u) ? (1.0f - wy) : 0.0f) +
                   (((unsigned)(r0 + 1) < 256u) ? wy : 0.0f);
        if (t <= e2b) acc += ux * uy;
    }
    acc += __shfl_down(acc, 8, 16);
    acc += __shfl_down(acc, 4, 16);
    acc += __shfl_down(acc, 2, 16);
    acc += __shfl_down(acc, 1, 16);
    if (slane == 0 && valid) {
        float m = fmaxf(acc + (float)count, DEN_EPS);
        minv[angle * NUMBIN + bin] = m;
        minv[(angle + NANG_HALF) * NUMBIN + (NUMBIN - 1 - bin)] = m;
    }
}

// ---------------- subset forward projection (diffs), j = 1..3 -------------
__global__ __launch_bounds__(256)
void fp_sub_kernel(const float* __restrict__ Qn, const float* __restrict__ Qt,
                   const float* __restrict__ sino, const float* __restrict__ minv,
                   float* __restrict__ gOut,
                   const float* __restrict__ cosA, const float* __restrict__ sinA,
                   int j) {
    const int wid = threadIdx.x >> 6, lane = threadIdx.x & 63;
    const int sub = lane >> 4, slane = lane & 15;
    int unit = blockIdx.x;
    int ai = unit / UPA;
    int bin = (unit - ai * UPA) * 16 + wid * 4 + sub;
    bool valid = bin < NUMBIN;
    int angle = j + NS * ai;                 // < 180
    RaySetup R = ray_setup_ab(angle, valid ? bin : 0, cosA, sinA, slane);
    const float* img = (R.useT ? Qt : Qn) + (QW + 1) * 2;
    float acc = march(img, R.u, R.v, R.du, R.dv, valid ? R.nc : 0);
    acc += __shfl_down(acc, 8, 16);
    acc += __shfl_down(acc, 4, 16);
    acc += __shfl_down(acc, 2, 16);
    acc += __shfl_down(acc, 1, 16);
    if (slane == 0 && valid) {
        int b2 = NUMBIN - 1 - bin;
        int a2 = angle + NANG_HALF;
        gOut[ai * NUMBIN + bin] =
            (sino[angle * NUMBIN + bin] - acc) / minv[angle * NUMBIN + bin];
        gOut[(ai + NANG_SUBH) * NUMBIN + b2] =
            (sino[a2 * NUMBIN + b2] - acc) / minv[a2 * NUMBIN + b2];
    }
}

// ---------------- merged: residual(fk1) partials + iter2-subset-0 diffs ---
// Single march serves both outputs (subset-0 rays ARE residual rays).
// Distinct-slot plain stores for resP1 (consumed across dispatch boundary).
__global__ __launch_bounds__(256)
void fp_merged_kernel(const float* __restrict__ Qn, const float* __restrict__ Qt,
                      const float* __restrict__ sino, const float* __restrict__ minv,
                      float* __restrict__ gA,
                      const float* __restrict__ cosA, const float* __restrict__ sinA,
                      float* __restrict__ resP1) {
    __shared__ float part[4];
    float tot = res_block_total(blockIdx.x, Qn, Qt, sino, cosA, sinA, part,
                                minv, gA);
    if (threadIdx.x == 0) resP1[blockIdx.x] = tot;
}

// ---------------- residual(fk2): partials only ----------------
__global__ __launch_bounds__(256)
void fp_res2_kernel(const float* __restrict__ Qn, const float* __restrict__ Qt,
                    const float* __restrict__ sino,
                    const float* __restrict__ cosA, const float* __restrict__ sinA,
                    float* __restrict__ resP2) {
    __shared__ float part[4];
    float tot = res_block_total(blockIdx.x, Qn, Qt, sino, cosA, sinA, part,
                                nullptr, nullptr);
    if (threadIdx.x == 0) resP2[blockIdx.x] = tot;
}

// ---------------- select: reduce both partial arrays + write output ------
// f2 = res2>thr ? fk2 : (res1>thr ? fk1 : f0). fcur holds fk1 (written by
// bp(iter1,j=3)); fk2 is Qf canonical. Each block redundantly reduces the
// 2x4140 partials (~33 KB from L2/L3 — cheap, fully parallel).
__global__ __launch_bounds__(256)
void select_kernel(float* __restrict__ fcur,
                   const float* __restrict__ Qn, const float* __restrict__ f0,
                   const float* __restrict__ resP1,
                   const float* __restrict__ resP2) {
    __shared__ float b1[4], b2[4];
    const int tid = threadIdx.x;
    float a1 = 0.0f, a2 = 0.0f;
    for (int i = tid; i < HALF_UNITS; i += 256) {
        a1 += resP1[i];
        a2 += resP2[i];
    }
    #pragma unroll
    for (int off = 32; off; off >>= 1) {
        a1 += __shfl_down(a1, off);
        a2 += __shfl_down(a2, off);
    }
    if ((tid & 63) == 0) { b1[tid >> 6] = a1; b2[tid >> 6] = a2; }
    __syncthreads();
    bool upd1 = (b1[0] + b1[1] + b1[2] + b1[3]) > RES2_THRESH;
    bool upd2 = (b2[0] + b2[1] + b2[2] + b2[3]) > RES2_THRESH;
    int p = blockIdx.x * 256 + tid;
    int px = p & (NUMPIX - 1), py = p >> 8;
    float v = upd2 ? Qn[((py + 1) * QW + (px + 1)) * 2]
                   : (upd1 ? fcur[p] : f0[p]);
    fcur[p] = v;
}

// ---------------- backprojection + SART update ----------------
// Mirror-paired: angles a and a+180 share the sd chain (sd2 = 366 - sd;
// value2 = w*g2[365-i0] + (1-w)*g2[366-i0]; i0 in [2,363] so in-bounds).
// chooseFlag: reduce resP1 (grid-uniform -> embedded sync safe); cold branch
// uses {df0, raw f0}. Base pixel value read BEFORE the barrier (ty0's post-
// barrier store would race it). Quad stores spread across ty waves.
__global__ __launch_bounds__(256)
void bp_update_kernel(float* __restrict__ Qf, float* __restrict__ QTf,
                      const float* __restrict__ f0,
                      const float* __restrict__ gA, const float* __restrict__ gB,
                      const float* __restrict__ cosA, const float* __restrict__ sinA,
                      const float* __restrict__ resP1, float* __restrict__ fcur,
                      int j, int doClamp, int writeFcur, int chooseFlag) {
    __shared__ float part[4][64];
    const float* g = gA;
    bool hot = true;
    if (chooseFlag) {
        __shared__ float rbuf[4];
        float a = 0.0f;
        for (int i = threadIdx.x; i < HALF_UNITS; i += 256) a += resP1[i];
        #pragma unroll
        for (int off = 32; off; off >>= 1) a += __shfl_down(a, off);
        if ((threadIdx.x & 63) == 0) rbuf[threadIdx.x >> 6] = a;
        __syncthreads();
        float r1v = rbuf[0] + rbuf[1] + rbuf[2] + rbuf[3];
        if (!(r1v > RES2_THRESH)) { g = gB; hot = false; }
    }
    const int tx = threadIdx.x & 63;
    const int ty = threadIdx.x >> 6;
    int p = blockIdx.x * 64 + tx;
    int px = p & (NUMPIX - 1), py = p >> 8;
    float X = (float)px - CPIX, Y = (float)py - CPIX;
    // read base BEFORE the barrier (ty0 writes this cell after it)
    float base = hot ? Qf[((py + 1) * QW + (px + 1)) * 2] : f0[p];
    float acc = 0.0f;
    for (int i = ty; i < NANG_SUBH; i += 4) {
        int angle = j + NS * i;
        float ca = cosA[angle], sa = sinA[angle];
        float sd = fmaf(X, ca, fmaf(Y, sa, CDET));   // always in [2.7, 363.3]
        float fl = floorf(sd);
        float w = sd - fl;
        int i0 = (int)fl;
        f2u gv = *(const f2u*)(g + i * NUMBIN + i0);
        acc += fmaf(w, gv.y - gv.x, gv.x);
        // mirror angle (a+180): sd2 = 366 - sd
        f2u gw = *(const f2u*)(g + (i + NANG_SUBH) * NUMBIN + (365 - i0));
        acc += fmaf(w, gw.x - gw.y, gw.y);
    }
    part[ty][tx] = acc;
    __syncthreads();
    float s = part[0][tx] + part[1][tx] + part[2][tx] + part[3][tx];
    float bpv = (fabsf(s) > 1000.0f) ? 0.0f : s;
    float v = base + bpv * INV_DINV;
    if (doClamp) v = fmaxf(v, EPS_F);
    if (ty == 0) {
        Qf[((py + 1) * QW + (px + 1)) * 2]  = v;
        Qf[(py * QW + (px + 1)) * 2 + 1]    = v;
    } else if (ty == 1) {
        QTf[((px + 1) * QW + (py + 1)) * 2] = v;
        QTf[(px * QW + (py + 1)) * 2 + 1]   = v;
    } else if (ty == 2) {
        if (writeFcur) fcur[p] = v;          // fk1 snapshot (hot-path f1)
    }
}

extern "C" void kernel_launch(void* const* d_in, const int* in_sizes, int n_in,
                              void* d_out, int out_size, void* d_ws, size_t ws_size,
                              hipStream_t stream) {
    const float* f0 = (const float*)d_in[0];     // [256,256]
    const float* sino = (const float*)d_in[1];   // [360,367]
    float* fcur = (float*)d_out;                 // [256,256] output "f"
    float* ws = (float*)d_ws;

    float* cosA = ws + OFF_COS;
    float* sinA = ws + OFF_SIN;
    float* minv = ws + OFF_MINV;     // [360,367] indexed by global angle
    float* resP1 = ws + OFF_RESP1;   // residual-1 block partials [4140]
    float* resP2 = ws + OFF_RESP2;   // residual-2 block partials [4140]
    float* Qf   = ws + OFF_Q;        // quad image (normal) — canonical fk
    float* QTf  = ws + OFF_QT;       // quad image (transposed)
    float* dfA  = ws + OFF_DIFF;     // working diffs
    float* df0  = ws + OFF_DIFF0;    // iter1-j0 diffs, pristine (cold branch)

    // 18 dispatches, zero atomics. init folds trig/quads + Minv + the
    // iter1-j0 FP (raw-f0 march; writes dfA & df0). fp_merged dedupes
    // subset-0 (one march serves residual + gA). select#1 folded into bp
    // via resP1 redundant reduce.
    init_minv_kernel<<<HALF_UNITS, 256, 0, stream>>>(
        cosA, sinA, Qf, QTf, minv, dfA, df0, f0, sino);

    // ---- iteration 1 (j0 FP came from init) ----
    bp_update_kernel<<<NPIX2 / 64, 256, 0, stream>>>(
        Qf, QTf, f0, dfA, df0, cosA, sinA, resP1, fcur,
        0, 0, 0, 0);
    for (int j = 1; j < NS; j++) {
        fp_sub_kernel<<<SUB_UNITS, 256, 0, stream>>>(
            Qf, QTf, sino, minv, dfA, cosA, sinA, j);
        bp_update_kernel<<<NPIX2 / 64, 256, 0, stream>>>(
            Qf, QTf, f0, dfA, df0, cosA, sinA, resP1, fcur,
            j, (j == NS - 1) ? 1 : 0, (j == NS - 1) ? 1 : 0, 0);
    }
    // ---- iteration boundary: residual(fk1) partials + iter2-j0 diffs ----
    fp_merged_kernel<<<HALF_UNITS, 256, 0, stream>>>(
        Qf, QTf, sino, minv, dfA, cosA, sinA, resP1);
    bp_update_kernel<<<NPIX2 / 64, 256, 0, stream>>>(
        Qf, QTf, f0, dfA, df0, cosA, sinA, resP1, fcur,
        0, 0, 0, 1);
    // ---- iteration 2, subsets 1..3 ----
    for (int j = 1; j < NS; j++) {
        fp_sub_kernel<<<SUB_UNITS, 256, 0, stream>>>(
            Qf, QTf, sino, minv, dfA, cosA, sinA, j);
        bp_update_kernel<<<NPIX2 / 64, 256, 0, stream>>>(
            Qf, QTf, f0, dfA, df0, cosA, sinA, resP1, fcur,
            j, (j == NS - 1) ? 1 : 0, 0, 0);
    }
    // ---- final residual partials + select ----
    fp_res2_kernel<<<HALF_UNITS, 256, 0, stream>>>(
        Qf, QTf, sino, cosA, sinA, resP2);
    select_kernel<<<NPIX2 / 256, 256, 0, stream>>>(
        fcur, Qf, f0, resP1, resP2);
}

// Round 8
// 220.970 us; speedup vs baseline: 1.0646x; 1.0646x over previous
//
#include <hip/hip_runtime.h>
#include <math.h>

#define NUMPIX 256
#define NUMBIN 367
#define NUMTHETA 360
#define NS 4
#define NT 367
#define NPIX2 (NUMPIX * NUMPIX)          // 65536
#define NANG_SUB (NUMTHETA / NS)         // 90
#define NRAYS_SUB (NANG_SUB * NUMBIN)    // 33030

// 180-degree mirror symmetry: FP[a+180][b] == FP[a][366-b] exactly (same
// bilinear sample points, reversed t order; t-grid is symmetric). All ray
// marches compute only angles [0,180) and emit both the ray and its mirror.
#define NANG_HALF 180
#define NANG_SUBH (NANG_SUB / 2)             // 45

// angle-major ray units: 23 units/angle x 16 rays/unit (bin 367 padded+masked)
#define UPA 23
#define HALF_UNITS (NANG_HALF * UPA)         // 4140 (residual + minv)
#define SUB_UNITS  (NANG_SUBH * UPA)         // 1035 (subset FP)

#define CDET 183.0f
#define CPIX 127.5f
#define TOFF 183.0f                      // (NT-1)/2
#define DEN_EPS 1e-6f
#define EPS_F 2.2204460492503131e-16f    // float64 eps
#define RES2_THRESH 1e-4f                // (0.01)^2
#define INV_DINV (1.0f / 90.0f)          // backproject(ones) == 90 exactly

// quad-interleaved image: element (r,c) = float2(img[r][c], img[r+1][c])
// rows r in [-1,256] stored at +1 (258 rows), cols c in [-1,258] at +1.
// Pixel (py,px) lives at Qf[(py+1)*QW+px+1].x — canonical fk storage.
// NOTE: march clamps coords to [-1,256]; the clamp is the TAIL MASK for
// overshoot lanes of the rounded-up chunk loop. Do NOT remove it.
// Grid-wide-sync fusion abandoned (r10/r11: co-residency not reliable).
// ROUND-2/3 LESSON: no same-LINE contended device atomics where the issuer
// waits on completion — 4129 RMWs to one line ~160 us (r2/r3).
// ROUND-5 LESSON: even a PADDED 64-slot fan-in + last-block select regressed
// (+22 us: contended completion-waits + a single CU writing the output while
// 255 idle). The r1/r4-proven pattern stands: distinct-slot plain stores +
// consumer-side redundant reduce across a dispatch boundary. ZERO atomics.
// ROUND-4/6 LESSON: ~7-9 us per dispatch boundary dominates (~150 us of 222
// at 19 dispatches) — but boundary cuts only pay if the folded work keeps
// its efficient form.
// ROUND-7 LESSON: folding fp_sub(j0) into init regressed +13 us — the fold
// must march RAW f0 (quad images are built in the same dispatch) at 4 scalar
// gathers/sample ~= +22 us, swamping the ~9 us boundary saving. Reverted.
// Remaining wall: ~17 serial boundaries x ~8.5 us (fp->bp dependency chain);
// no safe structural lever left without grid sync.
#define QW 260                           // float2 stride
#define QROWS 258
#define QN2 (QW * QROWS)                 // 67080 float2
#define QNF (QN2 * 2)                    // 134160 floats

typedef float f4q __attribute__((ext_vector_type(4), aligned(8)));
typedef float f2u __attribute__((ext_vector_type(2), aligned(4)));

// ---- workspace layout (in floats) ----
#define OFF_COS    0
#define OFF_SIN    (OFF_COS + NUMTHETA)            // 360
#define OFF_MINV   (OFF_SIN + NUMTHETA)            // 720
#define OFF_RESP1  (OFF_MINV + NUMTHETA * NUMBIN)  // 4140 block partials
#define OFF_RESP2  (OFF_RESP1 + HALF_UNITS + 4)    // 4140 block partials
#define OFF_FK1    (OFF_RESP2 + HALF_UNITS + 4)    // fk1 snapshot [65536]
#define OFF_Q      (OFF_FK1 + NPIX2)
#define OFF_QT     (OFF_Q + QNF)
#define OFF_DIFF   (OFF_QT + QNF)                  // working diffs [90,367]
#define OFF_DIFF0  (OFF_DIFF + NRAYS_SUB + 2)      // iter1-j0 diffs (cold path)

// generic t-interval clip: keep c0 + rate*tt within (bLo, bHi)
__device__ __forceinline__ void clip_axis2(float c0, float rate,
                                           float bLo, float bHi,
                                           float& lo, float& hi) {
    if (fabsf(rate) > 1e-6f) {
        float inv = 1.0f / rate;
        float a = (bLo - c0) * inv;
        float b = (bHi - c0) * inv;
        lo = fmaxf(lo, fminf(a, b));
        hi = fminf(hi, fmaxf(a, b));
    } else if (c0 <= bLo || c0 >= bHi) {
        lo = 1e9f; hi = -1e9f;
    }
}

// sampled t-range in 16-sample chunks; coords stay within clamp range
__device__ __forceinline__ int ray_chunks16(float x0, float y0, float ca, float sa,
                                            int& itlo) {
    float lo = -1e9f, hi = 1e9f;
    clip_axis2(x0, -sa, -2.0f, 257.0f, lo, hi);
    clip_axis2(y0,  ca, -2.0f, 257.0f, lo, hi);
    if (hi < lo) { itlo = 0; return 0; }
    int a = (int)floorf(lo + TOFF) - 1; if (a < 0) a = 0;
    int b = (int)ceilf(hi + TOFF) + 1;  if (b > NT - 1) b = NT - 1;
    itlo = a;
    if (b < a) return 0;
    return (b - a + 16) >> 4;
}

struct RaySetup {
    int nc;
    float u, v, du, dv;
    bool useT;
};

__device__ __forceinline__ RaySetup ray_setup_ab(int angle, int bin,
                                                 const float* __restrict__ cosA,
                                                 const float* __restrict__ sinA,
                                                 int slane) {
    RaySetup R;
    float ca = cosA[angle], sa = sinA[angle];
    float s = (float)bin - CDET;
    float x0 = fmaf(s, ca, CPIX);             // x(tt) = x0 - tt*sa
    float y0 = fmaf(s, sa, CPIX);             // y(tt) = y0 + tt*ca
    int itlo;
    R.nc = ray_chunks16(x0, y0, ca, sa, itlo);
    R.useT = fabsf(ca) > fabsf(sa);           // uniform per sub-group
    float u0 = R.useT ? y0 : x0, du = R.useT ? ca : -sa;   // fast (contiguous)
    float v0 = R.useT ? x0 : y0, dv = R.useT ? -sa : ca;   // slow (strided)
    float tt0 = (float)(itlo + slane) - TOFF;
    R.u = fmaf(tt0, du, u0);
    R.v = fmaf(tt0, dv, v0);
    R.du = du; R.dv = dv;
    return R;
}

// one clamped bilinear sample from a quad image
__device__ __forceinline__ float bilin(const float* __restrict__ img,
                                       float u, float v) {
    float uc = fminf(fmaxf(u, -1.0f), 256.0f);
    float vc = fminf(fmaxf(v, -1.0f), 256.0f);
    float fu = floorf(uc), fv = floorf(vc);
    float wu = uc - fu, wv = vc - fv;
    int idx = (int)fmaf(fv, (float)QW, fu);
    f4q q = *(const f4q*)(img + idx * 2);
    float t = fmaf(wu, q.z - q.x, q.x);
    float b = fmaf(wu, q.w - q.y, q.y);
    return fmaf(wv, b - t, t);
}

// chunk loop unrolled x4 with 4 independent accumulators (r6: latency-bound
// marches want 4 gathers in flight). Sum-order delta ~1e-7 rel.
__device__ __forceinline__ float march(const float* __restrict__ img,
                                       float u, float v, float du, float dv,
                                       int nc) {
    const float du16 = du * 16.0f, dv16 = dv * 16.0f;
    float a0 = 0.0f, a1 = 0.0f, a2 = 0.0f, a3 = 0.0f;
    int ic = 0;
    for (; ic + 3 < nc; ic += 4) {
        a0 += bilin(img, u, v);
        a1 += bilin(img, u + du16, v + dv16);
        a2 += bilin(img, u + du16 * 2.0f, v + dv16 * 2.0f);
        a3 += bilin(img, u + du16 * 3.0f, v + dv16 * 3.0f);
        u += du16 * 4.0f; v += dv16 * 4.0f;
    }
    for (; ic < nc; ++ic) {
        a0 += bilin(img, u, v);
        u += du16; v += dv16;
    }
    return (a0 + a1) + (a2 + a3);
}

// residual block-unit (angle-major): marches 16 rays of fk, returns block
// total of (base + mirror) squared diffs to ALL threads. If gA != nullptr
// and this block's angle is subset-0 (angle%4==0), also emits the iter2-j0
// diffs from the SAME march (dedupe: those rays coincide with residual rays).
__device__ __forceinline__ float res_block_total(
        int unit, const float* __restrict__ Qn, const float* __restrict__ Qt,
        const float* __restrict__ sino,
        const float* __restrict__ cosA, const float* __restrict__ sinA,
        float* partLds, const float* __restrict__ minv, float* __restrict__ gA) {
    const int wid = threadIdx.x >> 6, lane = threadIdx.x & 63;
    const int sub = lane >> 4, slane = lane & 15;
    int angle = unit / UPA;
    int bin = (unit - angle * UPA) * 16 + wid * 4 + sub;
    bool valid = bin < NUMBIN;
    RaySetup R = ray_setup_ab(angle, valid ? bin : 0, cosA, sinA, slane);
    const float* img = (R.useT ? Qt : Qn) + (QW + 1) * 2;
    float acc = march(img, R.u, R.v, R.du, R.dv, valid ? R.nc : 0);
    acc += __shfl_down(acc, 8, 16);
    acc += __shfl_down(acc, 4, 16);
    acc += __shfl_down(acc, 2, 16);
    acc += __shfl_down(acc, 1, 16);
    float d2 = 0.0f;
    if (slane == 0 && valid) {
        int b2 = NUMBIN - 1 - bin;
        float s1 = sino[angle * NUMBIN + bin];
        float s2 = sino[(angle + NANG_HALF) * NUMBIN + b2];
        float d = acc - s1, dm = acc - s2;
        d2 = d * d + dm * dm;
        if (gA != nullptr && (angle & 3) == 0) {
            int ai = angle >> 2;
            gA[ai * NUMBIN + bin] = (s1 - acc) / minv[angle * NUMBIN + bin];
            gA[(ai + NANG_SUBH) * NUMBIN + b2] =
                (s2 - acc) / minv[(angle + NANG_HALF) * NUMBIN + b2];
        }
    }
    d2 += __shfl_down(d2, 16);
    d2 += __shfl_down(d2, 32);
    if (lane == 0) partLds[wid] = d2;
    __syncthreads();
    return partLds[0] + partLds[1] + partLds[2] + partLds[3];
}

// ---------------- init + Minv in one dispatch ----------------
// idx-gated portion: trig tables + quad images. unit portion: edge-shortcut
// Minv for all 180 half-angles via own per-ray __sincosf (normalizer only,
// ~1e-6 rel). NOTE (r7): do NOT fold the j0 FP in here — it would have to
// march raw f0 with scalar gathers (+22 us > 9 us boundary saving).
__global__ __launch_bounds__(256)
void init_minv_kernel(float* __restrict__ cosA, float* __restrict__ sinA,
                      float* __restrict__ Qf, float* __restrict__ QTf,
                      float* __restrict__ minv,
                      const float* __restrict__ f0) {
    int idx = blockIdx.x * blockDim.x + threadIdx.x;
    if (idx < NUMTHETA) {
        float th = (float)((double)idx * 0.017453292519943295);
        cosA[idx] = (float)cos((double)th);
        sinA[idx] = (float)sin((double)th);
    }
    if (idx < QN2) {
        int qr = idx / QW, qc = idx - qr * QW;
        int r = qr - 1, c = qc - 1;                 // r in [-1,256], c in [-1,258]
        bool cv = ((unsigned)c < 256u);
        bool rv0 = ((unsigned)r < 256u), rv1 = ((unsigned)(r + 1) < 256u);
        float a = (cv && rv0) ? f0[r * NUMPIX + c] : 0.0f;
        float b = (cv && rv1) ? f0[(r + 1) * NUMPIX + c] : 0.0f;
        Qf[idx * 2] = a;  Qf[idx * 2 + 1] = b;
        float ta = (cv && rv0) ? f0[c * NUMPIX + r] : 0.0f;
        float tb = (cv && rv1) ? f0[c * NUMPIX + (r + 1)] : 0.0f;
        QTf[idx * 2] = ta;  QTf[idx * 2 + 1] = tb;
    }

    const int lane = threadIdx.x & 63;
    const int wid = threadIdx.x >> 6;
    const int sub = lane >> 4, slane = lane & 15;
    int unit = blockIdx.x;
    int angle = unit / UPA;                  // [0,180), uniform per block
    int bin = (unit - angle * UPA) * 16 + wid * 4 + sub;
    bool valid = bin < NUMBIN;

    float th = (float)((double)angle * 0.017453292519943295);
    float ca, sa;
    __sincosf(th, &sa, &ca);
    float s = (float)(valid ? bin : 0) - CDET;
    float x0 = fmaf(s, ca, CPIX);
    float y0 = fmaf(s, sa, CPIX);
    float acc = 0.0f;
    int count = 0;
    float lo = -1e9f, hi = 1e9f;
    clip_axis2(x0, -sa, -2.0f, 257.0f, lo, hi);
    clip_axis2(y0,  ca, -2.0f, 257.0f, lo, hi);
    int e1a = 0, e1b = -1, e2a = 0, e2b = -1;
    if (hi >= lo) {
        int itA = (int)floorf(lo + TOFF) - 1; if (itA < 0) itA = 0;
        int itB = (int)ceilf(hi + TOFF) + 1;  if (itB > NT - 1) itB = NT - 1;
        if (itB >= itA) {
            // strict interior: both coords in (0.05, 254.95) -> weight exactly 1
            float ilo = -1e9f, ihi = 1e9f;
            clip_axis2(x0, -sa, 0.05f, 254.95f, ilo, ihi);
            clip_axis2(y0,  ca, 0.05f, 254.95f, ilo, ihi);
            int jA = 1, jB = 0;
            if (ihi >= ilo) {
                jA = (int)ceilf(ilo + TOFF) + 1;
                jB = (int)floorf(ihi + TOFF) - 1;
                if (jA < itA) jA = itA;
                if (jB > itB) jB = itB;
            }
            if (jB >= jA) {
                count = jB - jA + 1;
                e1a = itA; e1b = jA - 1;
                e2a = jB + 1; e2b = itB;
            } else {
                e1a = itA; e1b = itB;       // no interior: one full edge loop
            }
        }
    }
    #pragma unroll 1
    for (int base = e1a; base <= e1b; base += 16) {
        int t = base + slane;
        float tt = (float)t - TOFF;
        float x = fmaf(-tt, sa, x0);
        float y = fmaf(tt, ca, y0);
        float fx = floorf(x), fy = floorf(y);
        float wx = x - fx, wy = y - fy;
        int c0 = (int)fx, r0 = (int)fy;
        float ux = (((unsigned)c0 < 256u) ? (1.0f - wx) : 0.0f) +
                   (((unsigned)(c0 + 1) < 256u) ? wx : 0.0f);
        float uy = (((unsigned)r0 < 256u) ? (1.0f - wy) : 0.0f) +
                   (((unsigned)(r0 + 1) < 256u) ? wy : 0.0f);
        if (t <= e1b) acc += ux * uy;
    }
    #pragma unroll 1
    for (int base = e2a; base <= e2b; base += 16) {
        int t = base + slane;
        float tt = (float)t - TOFF;
        float x = fmaf(-tt, sa, x0);
        float y = fmaf(tt, ca, y0);
        float fx = floorf(x), fy = floorf(y);
        float wx = x - fx, wy = y - fy;
        int c0 = (int)fx, r0 = (int)fy;
        float ux = (((unsigned)c0 < 256u) ? (1.0f - wx) : 0.0f) +
                   (((unsigned)(c0 + 1) < 256u) ? wx : 0.0f);
        float uy = (((unsigned)r0 < 256u) ? (1.0f - wy) : 0.0f) +
                   (((unsigned)(r0 + 1) < 256u) ? wy : 0.0f);
        if (t <= e2b) acc += ux * uy;
    }
    acc += __shfl_down(acc, 8, 16);
    acc += __shfl_down(acc, 4, 16);
    acc += __shfl_down(acc, 2, 16);
    acc += __shfl_down(acc, 1, 16);
    if (slane == 0 && valid) {
        float m = fmaxf(acc + (float)count, DEN_EPS);
        minv[angle * NUMBIN + bin] = m;
        minv[(angle + NANG_HALF) * NUMBIN + (NUMBIN - 1 - bin)] = m;
    }
}

// ---------------- subset forward projection (diffs) ----------------
// gDup != nullptr (iter1 j0 only): duplicate the diffs into df0, preserved
// as the pristine from-f0 diffs for the cold (res1<=thr) branch.
__global__ __launch_bounds__(256)
void fp_sub_kernel(const float* __restrict__ Qn, const float* __restrict__ Qt,
                   const float* __restrict__ sino, const float* __restrict__ minv,
                   float* __restrict__ gOut, float* __restrict__ gDup,
                   const float* __restrict__ cosA, const float* __restrict__ sinA,
                   int j) {
    const int wid = threadIdx.x >> 6, lane = threadIdx.x & 63;
    const int sub = lane >> 4, slane = lane & 15;
    int unit = blockIdx.x;
    int ai = unit / UPA;
    int bin = (unit - ai * UPA) * 16 + wid * 4 + sub;
    bool valid = bin < NUMBIN;
    int angle = j + NS * ai;                 // < 180
    RaySetup R = ray_setup_ab(angle, valid ? bin : 0, cosA, sinA, slane);
    const float* img = (R.useT ? Qt : Qn) + (QW + 1) * 2;
    float acc = march(img, R.u, R.v, R.du, R.dv, valid ? R.nc : 0);
    acc += __shfl_down(acc, 8, 16);
    acc += __shfl_down(acc, 4, 16);
    acc += __shfl_down(acc, 2, 16);
    acc += __shfl_down(acc, 1, 16);
    if (slane == 0 && valid) {
        int b2 = NUMBIN - 1 - bin;
        int a2 = angle + NANG_HALF;
        float g1 = (sino[angle * NUMBIN + bin] - acc) / minv[angle * NUMBIN + bin];
        float g2 = (sino[a2 * NUMBIN + b2] - acc) / minv[a2 * NUMBIN + b2];
        gOut[ai * NUMBIN + bin] = g1;
        gOut[(ai + NANG_SUBH) * NUMBIN + b2] = g2;
        if (gDup != nullptr) {
            gDup[ai * NUMBIN + bin] = g1;
            gDup[(ai + NANG_SUBH) * NUMBIN + b2] = g2;
        }
    }
}

// ---------------- merged: residual(fk1) partials + iter2-subset-0 diffs ---
// Single march serves both outputs (subset-0 rays ARE residual rays).
// Distinct-slot plain stores for resP1 (consumed across dispatch boundary).
__global__ __launch_bounds__(256)
void fp_merged_kernel(const float* __restrict__ Qn, const float* __restrict__ Qt,
                      const float* __restrict__ sino, const float* __restrict__ minv,
                      float* __restrict__ gA,
                      const float* __restrict__ cosA, const float* __restrict__ sinA,
                      float* __restrict__ resP1) {
    __shared__ float part[4];
    float tot = res_block_total(blockIdx.x, Qn, Qt, sino, cosA, sinA, part,
                                minv, gA);
    if (threadIdx.x == 0) resP1[blockIdx.x] = tot;
}

// ---------------- residual(fk2): partials only ----------------
__global__ __launch_bounds__(256)
void fp_res2_kernel(const float* __restrict__ Qn, const float* __restrict__ Qt,
                    const float* __restrict__ sino,
                    const float* __restrict__ cosA, const float* __restrict__ sinA,
                    float* __restrict__ resP2) {
    __shared__ float part[4];
    float tot = res_block_total(blockIdx.x, Qn, Qt, sino, cosA, sinA, part,
                                nullptr, nullptr);
    if (threadIdx.x == 0) resP2[blockIdx.x] = tot;
}

// ---------------- select: hot-path no-op fixup ----------------
// fcur ALREADY holds fk2 (bp(iter2,j3) wrote it). Hot path (res2>thr):
// reduce + early-exit, zero stores. Cold: overwrite with fk1 snapshot or f0.
__global__ __launch_bounds__(256)
void select_kernel(float* __restrict__ fcur,
                   const float* __restrict__ fk1, const float* __restrict__ f0,
                   const float* __restrict__ resP1,
                   const float* __restrict__ resP2) {
    __shared__ float b1[4], b2[4];
    const int tid = threadIdx.x;
    float a1 = 0.0f, a2 = 0.0f;
    for (int i = tid; i < HALF_UNITS; i += 256) {
        a1 += resP1[i];
        a2 += resP2[i];
    }
    #pragma unroll
    for (int off = 32; off; off >>= 1) {
        a1 += __shfl_down(a1, off);
        a2 += __shfl_down(a2, off);
    }
    if ((tid & 63) == 0) { b1[tid >> 6] = a1; b2[tid >> 6] = a2; }
    __syncthreads();
    bool upd1 = (b1[0] + b1[1] + b1[2] + b1[3]) > RES2_THRESH;
    bool upd2 = (b2[0] + b2[1] + b2[2] + b2[3]) > RES2_THRESH;
    if (upd2) return;                       // fcur == fk2 already
    int p = blockIdx.x * 256 + tid;
    fcur[p] = upd1 ? fk1[p] : f0[p];
}

// ---------------- backprojection + SART update ----------------
// Mirror-paired: angles a and a+180 share the sd chain (sd2 = 366 - sd;
// value2 = w*g2[365-i0] + (1-w)*g2[366-i0]; i0 in [2,363] so in-bounds).
// chooseFlag: reduce resP1 (grid-uniform -> embedded sync safe); cold branch
// uses {df0, raw f0}. Base pixel value read BEFORE the barrier (ty0's post-
// barrier store would race it). Quad stores spread across ty waves.
// writeSnap: ty2 wave snapshots v into fsnap (fk1 buffer at iter1-j3;
// fcur itself at iter2-j3, making select's hot path store-free).
__global__ __launch_bounds__(256)
void bp_update_kernel(float* __restrict__ Qf, float* __restrict__ QTf,
                      const float* __restrict__ f0,
                      const float* __restrict__ gA, const float* __restrict__ gB,
                      const float* __restrict__ cosA, const float* __restrict__ sinA,
                      const float* __restrict__ resP1, float* __restrict__ fsnap,
                      int j, int doClamp, int writeSnap, int chooseFlag) {
    __shared__ float part[4][64];
    const float* g = gA;
    bool hot = true;
    if (chooseFlag) {
        __shared__ float rbuf[4];
        float a = 0.0f;
        for (int i = threadIdx.x; i < HALF_UNITS; i += 256) a += resP1[i];
        #pragma unroll
        for (int off = 32; off; off >>= 1) a += __shfl_down(a, off);
        if ((threadIdx.x & 63) == 0) rbuf[threadIdx.x >> 6] = a;
        __syncthreads();
        float r1v = rbuf[0] + rbuf[1] + rbuf[2] + rbuf[3];
        if (!(r1v > RES2_THRESH)) { g = gB; hot = false; }
    }
    const int tx = threadIdx.x & 63;
    const int ty = threadIdx.x >> 6;
    int p = blockIdx.x * 64 + tx;
    int px = p & (NUMPIX - 1), py = p >> 8;
    float X = (float)px - CPIX, Y = (float)py - CPIX;
    // read base BEFORE the barrier (ty0 writes this cell after it)
    float base = hot ? Qf[((py + 1) * QW + (px + 1)) * 2] : f0[p];
    float acc = 0.0f;
    for (int i = ty; i < NANG_SUBH; i += 4) {
        int angle = j + NS * i;
        float ca = cosA[angle], sa = sinA[angle];
        float sd = fmaf(X, ca, fmaf(Y, sa, CDET));   // always in [2.7, 363.3]
        float fl = floorf(sd);
        float w = sd - fl;
        int i0 = (int)fl;
        f2u gv = *(const f2u*)(g + i * NUMBIN + i0);
        acc += fmaf(w, gv.y - gv.x, gv.x);
        // mirror angle (a+180): sd2 = 366 - sd
        f2u gw = *(const f2u*)(g + (i + NANG_SUBH) * NUMBIN + (365 - i0));
        acc += fmaf(w, gw.x - gw.y, gw.y);
    }
    part[ty][tx] = acc;
    __syncthreads();
    float s = part[0][tx] + part[1][tx] + part[2][tx] + part[3][tx];
    float bpv = (fabsf(s) > 1000.0f) ? 0.0f : s;
    float v = base + bpv * INV_DINV;
    if (doClamp) v = fmaxf(v, EPS_F);
    if (ty == 0) {
        Qf[((py + 1) * QW + (px + 1)) * 2]  = v;
        Qf[(py * QW + (px + 1)) * 2 + 1]    = v;
    } else if (ty == 1) {
        QTf[((px + 1) * QW + (py + 1)) * 2] = v;
        QTf[(px * QW + (py + 1)) * 2 + 1]   = v;
    } else if (ty == 2) {
        if (writeSnap) fsnap[p] = v;         // fk snapshot (fk1 buf / fcur)
    }
}

extern "C" void kernel_launch(void* const* d_in, const int* in_sizes, int n_in,
                              void* d_out, int out_size, void* d_ws, size_t ws_size,
                              hipStream_t stream) {
    const float* f0 = (const float*)d_in[0];     // [256,256]
    const float* sino = (const float*)d_in[1];   // [360,367]
    float* fcur = (float*)d_out;                 // [256,256] output "f"
    float* ws = (float*)d_ws;

    float* cosA = ws + OFF_COS;
    float* sinA = ws + OFF_SIN;
    float* minv = ws + OFF_MINV;     // [360,367] indexed by global angle
    float* resP1 = ws + OFF_RESP1;   // residual-1 block partials [4140]
    float* resP2 = ws + OFF_RESP2;   // residual-2 block partials [4140]
    float* fk1  = ws + OFF_FK1;      // fk1 snapshot (cold-path select)
    float* Qf   = ws + OFF_Q;        // quad image (normal) — canonical fk
    float* QTf  = ws + OFF_QT;       // quad image (transposed)
    float* dfA  = ws + OFF_DIFF;     // working diffs
    float* df0  = ws + OFF_DIFF0;    // iter1-j0 diffs, pristine (cold branch)

    // 19 dispatches, zero atomics (r6 structure — best measured, 222 us).
    // fp_merged dedupes subset-0 (one march serves residual + gA); df0
    // snapshot from fp_sub(j0) replaces the Q0 quad images; select#1 folded
    // into bp via resP1 redundant reduce; bp(iter2,j3) writes fcur=fk2 so
    // select's hot path is store-free.
    init_minv_kernel<<<HALF_UNITS, 256, 0, stream>>>(
        cosA, sinA, Qf, QTf, minv, f0);

    // ---- iteration 1 ----
    for (int j = 0; j < NS; j++) {
        fp_sub_kernel<<<SUB_UNITS, 256, 0, stream>>>(
            Qf, QTf, sino, minv, dfA, (j == 0) ? df0 : nullptr,
            cosA, sinA, j);
        bp_update_kernel<<<NPIX2 / 64, 256, 0, stream>>>(
            Qf, QTf, f0, dfA, df0, cosA, sinA, resP1, fk1,
            j, (j == NS - 1) ? 1 : 0, (j == NS - 1) ? 1 : 0, 0);
    }
    // ---- iteration boundary: residual(fk1) partials + iter2-j0 diffs ----
    fp_merged_kernel<<<HALF_UNITS, 256, 0, stream>>>(
        Qf, QTf, sino, minv, dfA, cosA, sinA, resP1);
    bp_update_kernel<<<NPIX2 / 64, 256, 0, stream>>>(
        Qf, QTf, f0, dfA, df0, cosA, sinA, resP1, fk1,
        0, 0, 0, 1);
    // ---- iteration 2, subsets 1..3 (j3 writes fcur = fk2) ----
    for (int j = 1; j < NS; j++) {
        fp_sub_kernel<<<SUB_UNITS, 256, 0, stream>>>(
            Qf, QTf, sino, minv, dfA, nullptr, cosA, sinA, j);
        bp_update_kernel<<<NPIX2 / 64, 256, 0, stream>>>(
            Qf, QTf, f0, dfA, df0, cosA, sinA, resP1, fcur,
            j, (j == NS - 1) ? 1 : 0, (j == NS - 1) ? 1 : 0, 0);
    }
    // ---- final residual partials + select (hot path store-free) ----
    fp_res2_kernel<<<HALF_UNITS, 256, 0, stream>>>(
        Qf, QTf, sino, cosA, sinA, resP2);
    select_kernel<<<NPIX2 / 256, 256, 0, stream>>>(
        fcur, fk1, f0, resP1, resP2);
}